// Round 4
// baseline (298.631 us; speedup 1.0000x reference)
//
#include <hip/hip_runtime.h>
#include <hip/hip_bf16.h>
#include <math.h>

#define B_SZ   4096
#define H_LEN  256
#define D_DIM  128
#define K_HEADS 4
#define H1_DIM 512
#define H2_DIM 256

#define CH     32     // history rows per chunk (32 -> 21 KB LDS -> 7 blocks/CU)
#define NCH    8      // chunks
#define TPAD   132    // tile row stride (floats): 16B-aligned; pooling reads conflict-free

// ---------------------------------------------------------------------------
// Kernel 1: single-pass multi-interest extraction. Block b = batch sample b.
// Each history row read from global exactly once. Small chunked LDS tile
// (17 KB) + 64-VGPR cap -> ~28 waves/CU for gather latency hiding.
// Softmax without max-subtraction (scores O(0.1); exp perfectly conditioned).
// ---------------------------------------------------------------------------
__global__ __launch_bounds__(256, 8) void interest_kernel(
    const int*   __restrict__ cand_ids,   // (B,)
    const int*   __restrict__ hist,       // (B, H)
    const float* __restrict__ table,      // (NUM_ITEMS, D)
    const float* __restrict__ Wp,         // (D, K) row-major
    float*       __restrict__ X)          // (B, 2D) output: [selected | cand]
{
    __shared__ float tile[CH * TPAD];     // 16896 B; tail-reused for partB/ivbuf
    __shared__ float wpt[K_HEADS * D_DIM];// Wp^T [k][d]           2 KB
    __shared__ float exps4[CH * 4];       // exp(score) [h][k]     512 B
    __shared__ float candv[D_DIM];        //                       512 B
    __shared__ int   rowids[H_LEN];       //                       1 KB
    __shared__ float lsumW[16];           // per-wave denom partials [w][k]
    __shared__ float simred[4][K_HEADS];
    __shared__ int   bestk;

    const int b    = blockIdx.x;
    const int t    = threadIdx.x;
    const int lane = t & 63, w = t >> 6;
    const int r    = t >> 3, q = t & 7;      // gather: 8 threads per row
    const int d    = t & 127, half = t >> 7; // pooling: 2 threads per d

    // --- stage Wp^T, candidate row, history ids ---
    if (t < D_DIM) {
        float4 w4 = ((const float4*)Wp)[t];   // Wp[d=t][0..3]
        wpt[0 * D_DIM + t] = w4.x;
        wpt[1 * D_DIM + t] = w4.y;
        wpt[2 * D_DIM + t] = w4.z;
        wpt[3 * D_DIM + t] = w4.w;
    }
    const int cand = cand_ids[b];
    if (t >= 128 && t < 160) {
        int c = t - 128;
        ((float4*)candv)[c] = ((const float4*)(table + (long long)cand * D_DIM))[c];
    }
    rowids[t] = hist[(long long)b * H_LEN + t];

    float a0 = 0.f, a1 = 0.f, a2 = 0.f, a3 = 0.f;  // pooling acc for (d,half)
    float l0 = 0.f, l1 = 0.f, l2 = 0.f, l3 = 0.f;  // wave-local denom partials

    for (int c = 0; c < NCH; ++c) {
        __syncthreads();   // tile/exps4 free (and staging ready on c==0)

        // --- gather 32 rows; thread (r,q) owns float4 columns q + 8j ---
        const int   row = rowids[(c << 5) + r];
        const float* rp = table + (long long)row * D_DIM + (q << 2);
        float4 v0 = *(const float4*)(rp + 0 * 32);
        float4 v1 = *(const float4*)(rp + 1 * 32);
        float4 v2 = *(const float4*)(rp + 2 * 32);
        float4 v3 = *(const float4*)(rp + 3 * 32);

        float s0 = 0.f, s1 = 0.f, s2 = 0.f, s3 = 0.f;
        float4 va;
        #define DO_J(J, VV)                                                     \
        {   va = VV;                                                            \
            const int cb = (q << 2) + (J << 5);                                 \
            float4 w0 = *(const float4*)(wpt + 0 * D_DIM + cb);                 \
            float4 w1 = *(const float4*)(wpt + 1 * D_DIM + cb);                 \
            float4 w2 = *(const float4*)(wpt + 2 * D_DIM + cb);                 \
            float4 w3 = *(const float4*)(wpt + 3 * D_DIM + cb);                 \
            s0 += va.x * w0.x + va.y * w0.y + va.z * w0.z + va.w * w0.w;        \
            s1 += va.x * w1.x + va.y * w1.y + va.z * w1.z + va.w * w1.w;        \
            s2 += va.x * w2.x + va.y * w2.y + va.z * w2.z + va.w * w2.w;        \
            s3 += va.x * w3.x + va.y * w3.y + va.z * w3.z + va.w * w3.w;        \
            *(float4*)(tile + r * TPAD + cb) = va;                              \
        }
        DO_J(0, v0) DO_J(1, v1) DO_J(2, v2) DO_J(3, v3)
        #undef DO_J

        // combine the 8 q-lanes of each row (lanes 8r..8r+7 adjacent)
        s0 += __shfl_xor(s0, 1); s0 += __shfl_xor(s0, 2); s0 += __shfl_xor(s0, 4);
        s1 += __shfl_xor(s1, 1); s1 += __shfl_xor(s1, 2); s1 += __shfl_xor(s1, 4);
        s2 += __shfl_xor(s2, 1); s2 += __shfl_xor(s2, 2); s2 += __shfl_xor(s2, 4);
        s3 += __shfl_xor(s3, 1); s3 += __shfl_xor(s3, 2); s3 += __shfl_xor(s3, 4);

        float e0 = expf(s0), e1 = expf(s1), e2 = expf(s2), e3 = expf(s3);
        if (q == 0) ((float4*)exps4)[r & 31] = make_float4(e0, e1, e2, e3);

        // wave-sum over this wave's 8 rows (butterfly over high lane bits only)
        float t0 = e0, t1 = e1, t2 = e2, t3 = e3;
        #pragma unroll
        for (int off = 8; off <= 32; off <<= 1) {
            t0 += __shfl_xor(t0, off);
            t1 += __shfl_xor(t1, off);
            t2 += __shfl_xor(t2, off);
            t3 += __shfl_xor(t3, off);
        }
        l0 += t0; l1 += t1; l2 += t2; l3 += t3;

        __syncthreads();   // tile + exps4 visible

        // --- pooling: acc[k][d] += sum over my 16 chunk rows ---
        #pragma unroll 8
        for (int i = 0; i < 16; ++i) {
            int hl = (half << 4) + i;
            float4 e4 = ((const float4*)exps4)[hl];   // broadcast
            float  vv = tile[hl * TPAD + d];          // conflict-free (2-way)
            a0 += e4.x * vv; a1 += e4.y * vv; a2 += e4.z * vv; a3 += e4.w * vv;
        }
    }

    __syncthreads();   // all pooling reads of tile done -> reuse tile memory
    float* partBp = tile;         // 512 floats
    float* ivbufp = tile + 512;   // 512 floats

    if (half == 1) ((float4*)partBp)[d] = make_float4(a0, a1, a2, a3);
    if (lane == 0) ((float4*)lsumW)[w]  = make_float4(l0, l1, l2, l3);
    __syncthreads();

    float s0 = 0.f, s1 = 0.f, s2 = 0.f, s3 = 0.f;
    if (half == 0) {
        float4 pb = ((const float4*)partBp)[d];
        float4 L0 = ((const float4*)lsumW)[0];
        float4 L1 = ((const float4*)lsumW)[1];
        float4 L2 = ((const float4*)lsumW)[2];
        float4 L3 = ((const float4*)lsumW)[3];
        float i0 = 1.f / (L0.x + L1.x + L2.x + L3.x);
        float i1 = 1.f / (L0.y + L1.y + L2.y + L3.y);
        float i2 = 1.f / (L0.z + L1.z + L2.z + L3.z);
        float i3 = 1.f / (L0.w + L1.w + L2.w + L3.w);
        a0 = (a0 + pb.x) * i0;
        a1 = (a1 + pb.y) * i1;
        a2 = (a2 + pb.z) * i2;
        a3 = (a3 + pb.w) * i3;
        ((float4*)ivbufp)[d] = make_float4(a0, a1, a2, a3);
        float cd = candv[d];
        s0 = a0 * cd; s1 = a1 * cd; s2 = a2 * cd; s3 = a3 * cd;
    }
    #pragma unroll
    for (int off = 32; off >= 1; off >>= 1) {
        s0 += __shfl_xor(s0, off);
        s1 += __shfl_xor(s1, off);
        s2 += __shfl_xor(s2, off);
        s3 += __shfl_xor(s3, off);
    }
    if (lane == 0) {
        simred[w][0] = s0; simred[w][1] = s1;
        simred[w][2] = s2; simred[w][3] = s3;
    }
    __syncthreads();

    if (t == 0) {
        float sim[4];
        #pragma unroll
        for (int k = 0; k < 4; ++k)
            sim[k] = simred[0][k] + simred[1][k] + simred[2][k] + simred[3][k];
        int best = 0;
        #pragma unroll
        for (int k = 1; k < 4; ++k) if (sim[k] > sim[best]) best = k;  // first-max
        bestk = best;
    }
    __syncthreads();

    float* xrow = X + (long long)b * (2 * D_DIM);
    if (t < 128) xrow[t] = ivbufp[t * 4 + bestk];
    else         xrow[t] = candv[t - 128];
}

// ---------------------------------------------------------------------------
// Kernel 2/3: C(M,N) = relu(A(M,K) @ W(K,N) + bias), all row-major fp32.
// 64x64 tile, BK=32, 256 threads, 4x4 micro-tile.
// ---------------------------------------------------------------------------
#define GT  64
#define GBK 32

__global__ __launch_bounds__(256) void gemm_bias_relu(
    const float* __restrict__ A, const float* __restrict__ W,
    const float* __restrict__ bias, float* __restrict__ C,
    int M, int N, int K)
{
    __shared__ float As[GBK * GT];   // [kk][m]
    __shared__ float Ws[GBK * GT];   // [kk][n]
    const int t  = threadIdx.x;
    const int tx = t & 15, ty = t >> 4;
    const int n0 = blockIdx.x * GT, m0 = blockIdx.y * GT;

    float acc[4][4] = {{0.f}};

    const int am = t >> 2, aq = t & 3;   // A: row am, k-cols aq*8 .. aq*8+7
    const int wk = t >> 3, wr = t & 7;   // W: row wk, n-cols wr*8 .. wr*8+7

    for (int k0 = 0; k0 < K; k0 += GBK) {
        float4 fa0 = *(const float4*)(A + (long long)(m0 + am) * K + k0 + aq * 8);
        float4 fa1 = *(const float4*)(A + (long long)(m0 + am) * K + k0 + aq * 8 + 4);
        float4 fw0 = *(const float4*)(W + (long long)(k0 + wk) * N + n0 + wr * 8);
        float4 fw1 = *(const float4*)(W + (long long)(k0 + wk) * N + n0 + wr * 8 + 4);
        __syncthreads();   // previous iter's reads done before overwrite
        As[(aq * 8 + 0) * GT + am] = fa0.x;
        As[(aq * 8 + 1) * GT + am] = fa0.y;
        As[(aq * 8 + 2) * GT + am] = fa0.z;
        As[(aq * 8 + 3) * GT + am] = fa0.w;
        As[(aq * 8 + 4) * GT + am] = fa1.x;
        As[(aq * 8 + 5) * GT + am] = fa1.y;
        As[(aq * 8 + 6) * GT + am] = fa1.z;
        As[(aq * 8 + 7) * GT + am] = fa1.w;
        *(float4*)(Ws + wk * GT + wr * 8)     = fw0;
        *(float4*)(Ws + wk * GT + wr * 8 + 4) = fw1;
        __syncthreads();
        #pragma unroll
        for (int kk = 0; kk < GBK; ++kk) {
            float4 a4 = *(const float4*)(As + kk * GT + ty * 4);
            float4 w4 = *(const float4*)(Ws + kk * GT + tx * 4);
            acc[0][0] += a4.x * w4.x; acc[0][1] += a4.x * w4.y;
            acc[0][2] += a4.x * w4.z; acc[0][3] += a4.x * w4.w;
            acc[1][0] += a4.y * w4.x; acc[1][1] += a4.y * w4.y;
            acc[1][2] += a4.y * w4.z; acc[1][3] += a4.y * w4.w;
            acc[2][0] += a4.z * w4.x; acc[2][1] += a4.z * w4.y;
            acc[2][2] += a4.z * w4.z; acc[2][3] += a4.z * w4.w;
            acc[3][0] += a4.w * w4.x; acc[3][1] += a4.w * w4.y;
            acc[3][2] += a4.w * w4.z; acc[3][3] += a4.w * w4.w;
        }
    }

    float4 bv = *(const float4*)(bias + n0 + tx * 4);
    #pragma unroll
    for (int i = 0; i < 4; ++i) {
        float4 c;
        c.x = fmaxf(acc[i][0] + bv.x, 0.f);
        c.y = fmaxf(acc[i][1] + bv.y, 0.f);
        c.z = fmaxf(acc[i][2] + bv.z, 0.f);
        c.w = fmaxf(acc[i][3] + bv.w, 0.f);
        *(float4*)(C + (long long)(m0 + ty * 4 + i) * N + n0 + tx * 4) = c;
    }
}

// ---------------------------------------------------------------------------
// Kernel 4: out[b] = sigmoid(h2[b] . W3 + b3)
// ---------------------------------------------------------------------------
__global__ __launch_bounds__(256) void head_kernel(
    const float* __restrict__ H2buf,   // (B, 256)
    const float* __restrict__ W3,      // (256, 1)
    const float* __restrict__ b3,
    float*       __restrict__ out)     // (B,)
{
    const int b = blockIdx.x * 256 + threadIdx.x;
    const float4* hp = (const float4*)(H2buf + (long long)b * H2_DIM);
    const float4* wp = (const float4*)W3;
    float acc = 0.f;
    #pragma unroll 8
    for (int i = 0; i < H2_DIM / 4; ++i) {
        float4 h = hp[i], wv = wp[i];
        acc += h.x * wv.x + h.y * wv.y + h.z * wv.z + h.w * wv.w;
    }
    float z = acc + b3[0];
    out[b] = 1.f / (1.f + expf(-z));
}

// ---------------------------------------------------------------------------
extern "C" void kernel_launch(void* const* d_in, const int* in_sizes, int n_in,
                              void* d_out, int out_size, void* d_ws, size_t ws_size,
                              hipStream_t stream) {
    // input order: user_ids, candidate_items, history_items, item_table, Wp,
    //              W1, b1, W2, b2, W3, b3
    const int*   cand  = (const int*)  d_in[1];
    const int*   hist  = (const int*)  d_in[2];
    const float* table = (const float*)d_in[3];
    const float* Wp    = (const float*)d_in[4];
    const float* W1    = (const float*)d_in[5];
    const float* b1    = (const float*)d_in[6];
    const float* W2    = (const float*)d_in[7];
    const float* b2    = (const float*)d_in[8];
    const float* W3    = (const float*)d_in[9];
    const float* b3    = (const float*)d_in[10];
    float* out = (float*)d_out;

    float* X   = (float*)d_ws;                       // (B, 256)   4 MB
    float* Hc1 = X   + (size_t)B_SZ * 2 * D_DIM;     // (B, 512)   8 MB
    float* Hc2 = Hc1 + (size_t)B_SZ * H1_DIM;        // (B, 256)   4 MB

    interest_kernel<<<B_SZ, 256, 0, stream>>>(cand, hist, table, Wp, X);
    gemm_bias_relu<<<dim3(H1_DIM / GT, B_SZ / GT), 256, 0, stream>>>(
        X, W1, b1, Hc1, B_SZ, H1_DIM, 2 * D_DIM);
    gemm_bias_relu<<<dim3(H2_DIM / GT, B_SZ / GT), 256, 0, stream>>>(
        Hc1, W2, b2, Hc2, B_SZ, H2_DIM, H1_DIM);
    head_kernel<<<B_SZ / 256, 256, 0, stream>>>(Hc2, W3, b3, out);
}

// Round 5
// 274.772 us; speedup vs baseline: 1.0868x; 1.0868x over previous
//
#include <hip/hip_runtime.h>
#include <hip/hip_bf16.h>
#include <math.h>

#define B_SZ   4096
#define H_LEN  256
#define D_DIM  128
#define K_HEADS 4
#define H1_DIM 512
#define H2_DIM 256

#define CH     64     // history rows per chunk (round-3 config: fastest measured)
#define NCH    4      // chunks
#define TPAD   132    // tile row stride (floats): 16B-aligned

typedef __attribute__((ext_vector_type(8))) short bf16x8;   // 8 bf16 (4 VGPRs)
typedef __attribute__((ext_vector_type(4))) float f32x4;

// ---------------------------------------------------------------------------
// Kernel 1: single-pass multi-interest extraction (round-3 structure, 106 us).
// Epilogue now emits bf16 X for the MFMA MLP tail. fp32 everywhere upstream
// of the argmax so interest selection is bit-stable vs reference.
// ---------------------------------------------------------------------------
__global__ __launch_bounds__(256, 4) void interest_kernel(
    const int*   __restrict__ cand_ids,   // (B,)
    const int*   __restrict__ hist,       // (B, H)
    const float* __restrict__ table,      // (NUM_ITEMS, D)
    const float* __restrict__ Wp,         // (D, K) row-major
    __hip_bfloat16* __restrict__ Xbf)     // (B, 2D) bf16: [selected | cand]
{
    __shared__ float tile[CH * TPAD];     // 33792 B; tail-reused for partB/ivbuf
    __shared__ float wpt[K_HEADS * D_DIM];// Wp^T [k][d]           2 KB
    __shared__ float exps4[CH * 4];       // exp(score) [h][k]     1 KB
    __shared__ float candv[D_DIM];        //                       512 B
    __shared__ int   rowids[H_LEN];       //                       1 KB
    __shared__ float lsumW[16];           // per-wave denom partials [w][k]
    __shared__ float simred[4][K_HEADS];
    __shared__ int   bestk;

    const int b    = blockIdx.x;
    const int t    = threadIdx.x;
    const int lane = t & 63, w = t >> 6;
    const int r    = t >> 2, q = t & 3;      // gather: 4 threads per row
    const int d    = t & 127, half = t >> 7; // pooling: 2 threads per d

    if (t < D_DIM) {
        float4 w4 = ((const float4*)Wp)[t];   // Wp[d=t][0..3]
        wpt[0 * D_DIM + t] = w4.x;
        wpt[1 * D_DIM + t] = w4.y;
        wpt[2 * D_DIM + t] = w4.z;
        wpt[3 * D_DIM + t] = w4.w;
    }
    const int cand = cand_ids[b];
    if (t >= 128 && t < 160) {
        int c = t - 128;
        ((float4*)candv)[c] = ((const float4*)(table + (long long)cand * D_DIM))[c];
    }
    rowids[t] = hist[(long long)b * H_LEN + t];

    float a0 = 0.f, a1 = 0.f, a2 = 0.f, a3 = 0.f;  // pooling acc for (d,half)
    float l0 = 0.f, l1 = 0.f, l2 = 0.f, l3 = 0.f;  // wave-local denom partials

    for (int c = 0; c < NCH; ++c) {
        __syncthreads();   // tile/exps4 free (and staging ready on c==0)

        // --- gather 64 rows; thread (r,q) owns float4 columns q+4j ---
        const int   row = rowids[(c << 6) + r];
        const float* rp = table + (long long)row * D_DIM + (q << 2);
        float4 v0 = *(const float4*)(rp + 0 * 16);
        float4 v1 = *(const float4*)(rp + 1 * 16);
        float4 v2 = *(const float4*)(rp + 2 * 16);
        float4 v3 = *(const float4*)(rp + 3 * 16);
        float4 v4 = *(const float4*)(rp + 4 * 16);
        float4 v5 = *(const float4*)(rp + 5 * 16);
        float4 v6 = *(const float4*)(rp + 6 * 16);
        float4 v7 = *(const float4*)(rp + 7 * 16);

        float s0 = 0.f, s1 = 0.f, s2 = 0.f, s3 = 0.f;
        float4 va;
        #define DO_J(J, VV)                                                     \
        {   va = VV;                                                            \
            const int cb = (q << 2) + (J << 4);                                 \
            float4 w0 = *(const float4*)(wpt + 0 * D_DIM + cb);                 \
            float4 w1 = *(const float4*)(wpt + 1 * D_DIM + cb);                 \
            float4 w2 = *(const float4*)(wpt + 2 * D_DIM + cb);                 \
            float4 w3 = *(const float4*)(wpt + 3 * D_DIM + cb);                 \
            s0 += va.x * w0.x + va.y * w0.y + va.z * w0.z + va.w * w0.w;        \
            s1 += va.x * w1.x + va.y * w1.y + va.z * w1.z + va.w * w1.w;        \
            s2 += va.x * w2.x + va.y * w2.y + va.z * w2.z + va.w * w2.w;        \
            s3 += va.x * w3.x + va.y * w3.y + va.z * w3.z + va.w * w3.w;        \
            *(float4*)(tile + r * TPAD + cb) = va;                              \
        }
        DO_J(0, v0) DO_J(1, v1) DO_J(2, v2) DO_J(3, v3)
        DO_J(4, v4) DO_J(5, v5) DO_J(6, v6) DO_J(7, v7)
        #undef DO_J

        // combine the 4 q-lanes of each row
        s0 += __shfl_xor(s0, 1); s0 += __shfl_xor(s0, 2);
        s1 += __shfl_xor(s1, 1); s1 += __shfl_xor(s1, 2);
        s2 += __shfl_xor(s2, 1); s2 += __shfl_xor(s2, 2);
        s3 += __shfl_xor(s3, 1); s3 += __shfl_xor(s3, 2);

        float e0 = expf(s0), e1 = expf(s1), e2 = expf(s2), e3 = expf(s3);
        if (q == 0) ((float4*)exps4)[r] = make_float4(e0, e1, e2, e3);

        // wave-sum over this wave's 16 rows
        float t0 = e0, t1 = e1, t2 = e2, t3 = e3;
        #pragma unroll
        for (int off = 4; off <= 32; off <<= 1) {
            t0 += __shfl_xor(t0, off);
            t1 += __shfl_xor(t1, off);
            t2 += __shfl_xor(t2, off);
            t3 += __shfl_xor(t3, off);
        }
        l0 += t0; l1 += t1; l2 += t2; l3 += t3;

        __syncthreads();   // tile + exps4 visible

        // --- pooling: acc[k][d] += sum over my 32 chunk rows ---
        #pragma unroll 8
        for (int i = 0; i < 32; ++i) {
            int hl = (half << 5) + i;
            float4 e4 = ((const float4*)exps4)[hl];   // broadcast
            float  vv = tile[hl * TPAD + d];
            a0 += e4.x * vv; a1 += e4.y * vv; a2 += e4.z * vv; a3 += e4.w * vv;
        }
    }

    __syncthreads();   // tile reads done -> reuse tile memory
    float* partBp = tile;         // 512 floats
    float* ivbufp = tile + 512;   // 512 floats

    if (half == 1) ((float4*)partBp)[d] = make_float4(a0, a1, a2, a3);
    if (lane == 0) ((float4*)lsumW)[w]  = make_float4(l0, l1, l2, l3);
    __syncthreads();

    float s0 = 0.f, s1 = 0.f, s2 = 0.f, s3 = 0.f;
    if (half == 0) {
        float4 pb = ((const float4*)partBp)[d];
        float4 L0 = ((const float4*)lsumW)[0];
        float4 L1 = ((const float4*)lsumW)[1];
        float4 L2 = ((const float4*)lsumW)[2];
        float4 L3 = ((const float4*)lsumW)[3];
        float i0 = 1.f / (L0.x + L1.x + L2.x + L3.x);
        float i1 = 1.f / (L0.y + L1.y + L2.y + L3.y);
        float i2 = 1.f / (L0.z + L1.z + L2.z + L3.z);
        float i3 = 1.f / (L0.w + L1.w + L2.w + L3.w);
        a0 = (a0 + pb.x) * i0;
        a1 = (a1 + pb.y) * i1;
        a2 = (a2 + pb.z) * i2;
        a3 = (a3 + pb.w) * i3;
        ((float4*)ivbufp)[d] = make_float4(a0, a1, a2, a3);
        float cd = candv[d];
        s0 = a0 * cd; s1 = a1 * cd; s2 = a2 * cd; s3 = a3 * cd;
    }
    #pragma unroll
    for (int off = 32; off >= 1; off >>= 1) {
        s0 += __shfl_xor(s0, off);
        s1 += __shfl_xor(s1, off);
        s2 += __shfl_xor(s2, off);
        s3 += __shfl_xor(s3, off);
    }
    if (lane == 0) {
        simred[w][0] = s0; simred[w][1] = s1;
        simred[w][2] = s2; simred[w][3] = s3;
    }
    __syncthreads();

    if (t == 0) {
        float sim[4];
        #pragma unroll
        for (int k = 0; k < 4; ++k)
            sim[k] = simred[0][k] + simred[1][k] + simred[2][k] + simred[3][k];
        int best = 0;
        #pragma unroll
        for (int k = 1; k < 4; ++k) if (sim[k] > sim[best]) best = k;  // first-max
        bestk = best;
    }
    __syncthreads();

    __hip_bfloat16* xrow = Xbf + (long long)b * (2 * D_DIM);
    if (t < 128) xrow[t] = __float2bfloat16(ivbufp[t * 4 + bestk]);
    else         xrow[t] = __float2bfloat16(candv[t - 128]);
}

// ---------------------------------------------------------------------------
// Convert W1 (256x512) -> W1t bf16 (512x256) and W2 (512x256) -> W2t bf16
// (256x512): weights transposed to (N, K) so MFMA B-fragments are contiguous.
// ---------------------------------------------------------------------------
__global__ __launch_bounds__(256) void convert_weights(
    const float* __restrict__ W1, const float* __restrict__ W2,
    __hip_bfloat16* __restrict__ W1t, __hip_bfloat16* __restrict__ W2t)
{
    int idx = blockIdx.x * 256 + threadIdx.x;
    if (idx < 2 * D_DIM * H1_DIM) {                    // 131072: W1
        int n = idx >> 8, k = idx & 255;               // W1t[n][k] = W1[k][n]
        W1t[idx] = __float2bfloat16(W1[k * H1_DIM + n]);
    } else {                                           // W2
        int j = idx - 2 * D_DIM * H1_DIM;
        int n = j >> 9, k = j & 511;                   // W2t[n][k] = W2[k][n]
        W2t[j] = __float2bfloat16(W2[k * H2_DIM + n]);
    }
}

// ---------------------------------------------------------------------------
// MFMA bf16 GEMM: C(M,N) = relu(A(M,K) @ B(K,N) + bias). B passed transposed
// (N,K) row-major. One wave = one 16x16 C tile; no LDS; direct b128 frag
// loads. A-frag: A[m=lane&15][k=quad*8+j]; B-frag: Bt[n=lane&15][k=quad*8+j];
// C: col=lane&15, row=quad*4+reg (verified layouts).
// ---------------------------------------------------------------------------
template<int N, int K, bool OUT_BF16>
__global__ __launch_bounds__(256) void mfma_mlp(
    const __hip_bfloat16* __restrict__ A,    // (M, K)
    const __hip_bfloat16* __restrict__ Bt,   // (N, K)
    const float* __restrict__ bias,          // (N,)
    void* __restrict__ Cout)                 // (M, N)
{
    const int t    = threadIdx.x;
    const int wave = t >> 6, lane = t & 63;
    const int lm   = lane & 15, quad = lane >> 4;
    const int n0   = blockIdx.x * 16;
    const int m0   = blockIdx.y * 64 + wave * 16;

    const __hip_bfloat16* Ap = A  + (long long)(m0 + lm) * K + quad * 8;
    const __hip_bfloat16* Bp = Bt + (long long)(n0 + lm) * K + quad * 8;

    f32x4 acc = {0.f, 0.f, 0.f, 0.f};
    for (int kc = 0; kc < K; kc += 256) {
        bf16x8 af[8], bfr[8];
        #pragma unroll
        for (int it = 0; it < 8; ++it) {
            af[it]  = *(const bf16x8*)(Ap + kc + it * 32);
            bfr[it] = *(const bf16x8*)(Bp + kc + it * 32);
        }
        #pragma unroll
        for (int it = 0; it < 8; ++it)
            acc = __builtin_amdgcn_mfma_f32_16x16x32_bf16(af[it], bfr[it], acc, 0, 0, 0);
    }

    const int n  = n0 + lm;
    const float bv = bias[n];
    #pragma unroll
    for (int i = 0; i < 4; ++i) {
        int m = m0 + quad * 4 + i;
        float v = fmaxf(acc[i] + bv, 0.f);
        if (OUT_BF16)
            ((__hip_bfloat16*)Cout)[(long long)m * N + n] = __float2bfloat16(v);
        else
            ((float*)Cout)[(long long)m * N + n] = v;
    }
}

// ---------------------------------------------------------------------------
// Kernel 4: out[b] = sigmoid(h2[b] . W3 + b3)
// ---------------------------------------------------------------------------
__global__ __launch_bounds__(256) void head_kernel(
    const float* __restrict__ H2buf,   // (B, 256) fp32
    const float* __restrict__ W3,      // (256, 1)
    const float* __restrict__ b3,
    float*       __restrict__ out)     // (B,)
{
    const int b = blockIdx.x * 256 + threadIdx.x;
    const float4* hp = (const float4*)(H2buf + (long long)b * H2_DIM);
    const float4* wp = (const float4*)W3;
    float acc = 0.f;
    #pragma unroll 8
    for (int i = 0; i < H2_DIM / 4; ++i) {
        float4 h = hp[i], wv = wp[i];
        acc += h.x * wv.x + h.y * wv.y + h.z * wv.z + h.w * wv.w;
    }
    float z = acc + b3[0];
    out[b] = 1.f / (1.f + expf(-z));
}

// ---------------------------------------------------------------------------
extern "C" void kernel_launch(void* const* d_in, const int* in_sizes, int n_in,
                              void* d_out, int out_size, void* d_ws, size_t ws_size,
                              hipStream_t stream) {
    const int*   cand  = (const int*)  d_in[1];
    const int*   hist  = (const int*)  d_in[2];
    const float* table = (const float*)d_in[3];
    const float* Wp    = (const float*)d_in[4];
    const float* W1    = (const float*)d_in[5];
    const float* b1    = (const float*)d_in[6];
    const float* W2    = (const float*)d_in[7];
    const float* b2    = (const float*)d_in[8];
    const float* W3    = (const float*)d_in[9];
    const float* b3    = (const float*)d_in[10];
    float* out = (float*)d_out;

    // ws layout (16B-aligned regions)
    char* p = (char*)d_ws;
    __hip_bfloat16* Xbf  = (__hip_bfloat16*)p;                  p += (size_t)B_SZ * 2 * D_DIM * 2;  // 2 MB
    __hip_bfloat16* Hc1  = (__hip_bfloat16*)p;                  p += (size_t)B_SZ * H1_DIM * 2;     // 4 MB
    float*          Hc2  = (float*)p;                           p += (size_t)B_SZ * H2_DIM * 4;     // 4 MB
    __hip_bfloat16* W1t  = (__hip_bfloat16*)p;                  p += (size_t)H1_DIM * 2 * D_DIM * 2;// 512 KB
    __hip_bfloat16* W2t  = (__hip_bfloat16*)p;                                                      // 512 KB

    convert_weights<<<(2 * D_DIM * H1_DIM + H1_DIM * H2_DIM) / 256, 256, 0, stream>>>(
        W1, W2, W1t, W2t);
    interest_kernel<<<B_SZ, 256, 0, stream>>>(cand, hist, table, Wp, Xbf);
    mfma_mlp<H1_DIM, 2 * D_DIM, true><<<dim3(H1_DIM / 16, B_SZ / 64), 256, 0, stream>>>(
        Xbf, W1t, b1, Hc1);
    mfma_mlp<H2_DIM, H1_DIM, false><<<dim3(H2_DIM / 16, B_SZ / 64), 256, 0, stream>>>(
        Hc1, W2t, b2, Hc2);
    head_kernel<<<B_SZ / 256, 256, 0, stream>>>(Hc2, W3, b3, out);
}